// Round 3
// baseline (171.668 us; speedup 1.0000x reference)
//
#include <hip/hip_runtime.h>

// x shape (B, T, A, D) = (256, 2048, 22, 2) fp32
#define BB 256
#define TT 2048
#define AD 44                    // floats per (b,t) row
#define AD4 11                   // float4 chunks per row
#define F4_PER_B (TT * AD4)      // 22528 float4 per batch
#define ELEMS 8                  // float4 per thread (copy role)
#define BLK_F4 (256 * ELEMS)     // 2048 float4 per copy block
#define BLOCKS_PER_B 11
#define NCOPY (BB * BLOCKS_PER_B)
#define NBLK (BB + NCOPY)        // 256 fixers + 2816 copiers = 3072 blocks

typedef float v4 __attribute__((ext_vector_type(4)));

// Single dispatch, two block roles, ZERO cross-block synchronization:
//  - fixer blocks (blockIdx < 256, launched first so they overlap the copy):
//    independently find the NaN row range of batch b by scanning column
//    (t,0,0) (gap rows are entirely NaN, so one float per row suffices;
//    all reads L3-hot from the harness re-poison fill), then write the
//    interpolated gap interior.
//  - copy blocks: streaming float4 copy, skipping all-NaN chunks.
// The two roles write disjoint output regions (gap interior vs rest), so
// no ordering, atomics, fences, workspace, or memset are needed.
__global__ __launch_bounds__(256) void interp_split(const v4* __restrict__ x4,
                                                    v4* __restrict__ out4) {
  const int tid = threadIdx.x;

  if (blockIdx.x >= BB) {
    // ---------------- copy role ----------------
    const int cid = blockIdx.x - BB;
    const int b = cid / BLOCKS_PER_B;
    const int blk_in_b = cid - b * BLOCKS_PER_B;
    const size_t base = (size_t)b * F4_PER_B + blk_in_b * BLK_F4;

    v4 v[ELEMS];
#pragma unroll
    for (int k = 0; k < ELEMS; ++k) {        // 8 independent loads in flight
      v[k] = x4[base + k * 256 + tid];
    }
#pragma unroll
    for (int k = 0; k < ELEMS; ++k) {
      const v4 w = v[k];
      const bool n = (w.x != w.x) || (w.y != w.y) || (w.z != w.z) || (w.w != w.w);
      if (!n) {
        // all-NaN chunk == gap row -> fixer writes it; skip (saves the
        // double-write). NT store: pure streaming, no reuse.
        __builtin_nontemporal_store(w, &out4[base + k * 256 + tid]);
      }
    }
    return;
  }

  // ---------------- fixer role ----------------
  const int b = blockIdx.x;
  const float* xf = (const float*)x4;
  const size_t fbase = (size_t)b * (TT * AD);

  // Scan first element of every row for NaN (8 independent strided loads).
  float c[8];
#pragma unroll
  for (int k = 0; k < 8; ++k) {
    c[k] = xf[fbase + (size_t)(k * 256 + tid) * AD];
  }
  int tmin = TT, tmax = -1;
#pragma unroll
  for (int k = 0; k < 8; ++k) {
    if (c[k] != c[k]) {
      const int t = k * 256 + tid;
      tmin = min(tmin, t);
      tmax = max(tmax, t);
    }
  }

  // Wave reduce, then cross-wave reduce (4 waves).
#pragma unroll
  for (int d = 32; d > 0; d >>= 1) {
    tmin = min(tmin, __shfl_xor(tmin, d));
    tmax = max(tmax, __shfl_xor(tmax, d));
  }
  __shared__ int smin[4], smax[4];
  __shared__ int s_sh, e_sh;
  const int wid = tid >> 6;
  if ((tid & 63) == 0) {
    smin[wid] = tmin;
    smax[wid] = tmax;
  }
  __syncthreads();
  if (tid == 0) {
    int a = TT, z = -1;
#pragma unroll
    for (int i = 0; i < 4; ++i) {
      a = min(a, smin[i]);
      z = max(z, smax[i]);
    }
    if (z < 0) {          // defensive: no NaN -> no-op fix, in-bounds reads
      s_sh = 0;
      e_sh = 1;
    } else {
      s_sh = a - 1;       // row before first NaN
      e_sh = z + 1;       // row after last NaN
    }
  }
  __syncthreads();
  const int s = s_sh;
  const int e = e_sh;

  // Boundary rows (NaN-free) -> LDS.
  __shared__ v4 sxs[AD4], sxe[AD4];
  const size_t base = (size_t)b * F4_PER_B;
  if (tid < AD4) sxs[tid] = x4[base + (size_t)s * AD4 + tid];
  if (tid >= 64 && tid < 64 + AD4) sxe[tid - 64] = x4[base + (size_t)e * AD4 + (tid - 64)];
  __syncthreads();

  // Interpolate gap interior rows s+1 .. e-1 (written exactly once, only
  // by this block -> disjoint from copy-role stores).
  const float inv = 1.0f / (float)(e - s);
  const int total = (e - s - 1) * AD4;
  for (int i = tid; i < total; i += 256) {
    const int dt = i / AD4;
    const int cch = i - dt * AD4;
    const int t = s + 1 + dt;
    const float w = (float)(dt + 1) * inv;   // (t - s)/(e - s)
    const float om = 1.0f - w;
    const v4 a = sxs[cch];
    const v4 z = sxe[cch];
    v4 r;
    r.x = a.x * om + z.x * w;
    r.y = a.y * om + z.y * w;
    r.z = a.z * om + z.z * w;
    r.w = a.w * om + z.w * w;
    out4[base + (size_t)t * AD4 + cch] = r;
  }
}

extern "C" void kernel_launch(void* const* d_in, const int* in_sizes, int n_in,
                              void* d_out, int out_size, void* d_ws, size_t ws_size,
                              hipStream_t stream) {
  const v4* x4 = (const v4*)d_in[0];
  v4* out4 = (v4*)d_out;
  interp_split<<<NBLK, 256, 0, stream>>>(x4, out4);
}